// Round 1
// baseline (909.899 us; speedup 1.0000x reference)
//
#include <hip/hip_runtime.h>
#include <hip/hip_bf16.h>

#define BB   256
#define NN   2207
#define MM   16
#define EE   16777216
#define CC1  12
#define CC2  4
#define HH1  256
#define HH2  64
#define KK1  (CC2*NN)          /* 8828 */
#define LN_EPS 1e-5f
#define BN_SCALE 0.9999950000374997f   /* 1/sqrt(1+1e-5) */

// ---------------- edge scatter: agg[dst] += x[src]*w ----------------
__global__ __launch_bounds__(256)
void k_edge(const int* __restrict__ src, const int* __restrict__ dst,
            const float* __restrict__ ew, const float* __restrict__ x,
            float* __restrict__ agg)
{
    int i = blockIdx.x * 256 + threadIdx.x;      // i in [0, E/4)
    const int4   s4 = reinterpret_cast<const int4*>(src)[i];
    const int4   d4 = reinterpret_cast<const int4*>(dst)[i];
    const float4 w4 = reinterpret_cast<const float4*>(ew)[i];
    unsafeAtomicAdd(&agg[d4.x], x[s4.x] * w4.x);
    unsafeAtomicAdd(&agg[d4.y], x[s4.y] * w4.y);
    unsafeAtomicAdd(&agg[d4.z], x[s4.z] * w4.z);
    unsafeAtomicAdd(&agg[d4.w], x[s4.w] * w4.w);
}

// ------- per-sample: h = relu(...), LayerNorm, conv1+bn, conv2+bn -> z -------
__global__ __launch_bounds__(256)
void k_sample(const float* __restrict__ x, const float* __restrict__ agg,
              const float* __restrict__ w_root, const float* __restrict__ w_rel,
              const float* __restrict__ b_rel,
              const float* __restrict__ ln_g, const float* __restrict__ ln_b,
              const float* __restrict__ gc1_w, const float* __restrict__ gc1_b,
              const float* __restrict__ bn1_g, const float* __restrict__ bn1_b,
              const float* __restrict__ gc2_w, const float* __restrict__ gc2_b,
              const float* __restrict__ bn2_g, const float* __restrict__ bn2_b,
              float* __restrict__ z)
{
    __shared__ float xs[NN], as[NN];
    __shared__ float gw1[CC1*MM], gb1[CC1], sb1[CC1], tb1[CC1];
    __shared__ float gw2[CC2*CC1], gb2[CC2], sb2[CC2], tb2[CC2];
    __shared__ float redS[4], redQ[4];
    __shared__ float s_mu, s_rs;

    const int b = blockIdx.x, t = threadIdx.x;
    const float* xb = x + b*NN;
    const float* ab = agg + b*NN;
    for (int n = t; n < NN; n += 256) { xs[n] = xb[n]; as[n] = ab[n]; }
    if (t < CC1*MM) gw1[t] = gc1_w[t];
    if (t >= 192 && t < 192+CC1) { int o = t-192; gb1[o]=gc1_b[o]; sb1[o]=BN_SCALE*bn1_g[o]; tb1[o]=bn1_b[o]; }
    if (t >= 208 && t < 208+CC2*CC1) gw2[t-208] = gc2_w[t-208];
    if (t >= 240 && t < 240+CC2) { int p=t-240; gb2[p]=gc2_b[p]; sb2[p]=BN_SCALE*bn2_g[p]; tb2[p]=bn2_b[p]; }

    float wr[MM], br[MM], wo[MM];
    #pragma unroll
    for (int m = 0; m < MM; ++m) { wr[m]=w_rel[m]; br[m]=b_rel[m]; wo[m]=w_root[m]; }
    __syncthreads();

    // pass 1: LN statistics over (N, M)
    float S = 0.f, Q = 0.f;
    for (int n = t; n < NN; n += 256) {
        float a = as[n], xv = xs[n];
        #pragma unroll
        for (int m = 0; m < MM; ++m) {
            float h = fmaxf(fmaf(a, wr[m], fmaf(xv, wo[m], br[m])), 0.f);
            S += h; Q += h*h;
        }
    }
    #pragma unroll
    for (int off = 32; off; off >>= 1) { S += __shfl_down(S, off); Q += __shfl_down(Q, off); }
    if ((t & 63) == 0) { redS[t>>6] = S; redQ[t>>6] = Q; }
    __syncthreads();
    if (t == 0) {
        float SS = redS[0]+redS[1]+redS[2]+redS[3];
        float QQ = redQ[0]+redQ[1]+redQ[2]+redQ[3];
        const float inv = 1.f / (float)(NN*MM);
        float mu = SS * inv;
        float var = QQ * inv - mu*mu;
        s_mu = mu; s_rs = rsqrtf(var + LN_EPS);
    }
    __syncthreads();
    const float mu = s_mu, rs = s_rs;

    // pass 2: normalize + conv1(bn,relu) + conv2(bn,relu) -> z[b, p*N+n]
    float* zb = z + (size_t)b * KK1;
    for (int n = t; n < NN; n += 256) {
        float a = as[n], xv = xs[n];
        float hn[MM];
        const float4* g4  = reinterpret_cast<const float4*>(ln_g + n*MM);
        const float4* be4 = reinterpret_cast<const float4*>(ln_b + n*MM);
        #pragma unroll
        for (int q = 0; q < 4; ++q) {
            float4 g = g4[q], be = be4[q];
            float gg[4]  = {g.x, g.y, g.z, g.w};
            float bb_[4] = {be.x, be.y, be.z, be.w};
            #pragma unroll
            for (int j = 0; j < 4; ++j) {
                int m = q*4 + j;
                float h = fmaxf(fmaf(a, wr[m], fmaf(xv, wo[m], br[m])), 0.f);
                hn[m] = (h - mu) * rs * gg[j] + bb_[j];
            }
        }
        float y1[CC1];
        #pragma unroll
        for (int o = 0; o < CC1; ++o) {
            float acc = gb1[o];
            #pragma unroll
            for (int m = 0; m < MM; ++m) acc = fmaf(gw1[o*MM+m], hn[m], acc);
            y1[o] = fmaxf(acc, 0.f) * sb1[o] + tb1[o];
        }
        #pragma unroll
        for (int p = 0; p < CC2; ++p) {
            float acc = gb2[p];
            #pragma unroll
            for (int o = 0; o < CC1; ++o) acc = fmaf(gw2[p*CC1+o], y1[o], acc);
            float y2 = fmaxf(acc, 0.f) * sb2[p] + tb2[p];
            zb[p*NN + n] = y2;
        }
    }
}

// ------------- FC1 GEMM: out1_raw[256,256] += z[256,8828] @ W1[8828,256] -------------
#define GK_CHUNK 288   /* 9*32; grid.z = 31 covers 31*288 = 8928 >= 8828 */
__global__ __launch_bounds__(256)
void k_fc1(const float* __restrict__ z, const float* __restrict__ W1,
           float* __restrict__ out1_raw)
{
    __shared__ float zs[64*36];   // [b][k], stride 36 (16B-aligned, conflict-lite)
    __shared__ float ws[32*68];   // [k][j], stride 68
    const int bt = blockIdx.x, jt = blockIdx.y, ks = blockIdx.z;
    const int t = threadIdx.x;
    const int tb = t >> 4, tj = t & 15;
    const int k0 = ks * GK_CHUNK;
    const int kend = min(k0 + GK_CHUNK, KK1);
    float acc[4][4] = {};
    const int zrow = t >> 2, zcol = (t & 3) * 8;
    const int wrow = t >> 3, wcol = (t & 7) * 8;

    for (int kc = k0; kc < kend; kc += 32) {
        // stage z tile (64 b x 32 k)
        const float* zsrc = z + (size_t)(bt*64 + zrow)*KK1 + kc + zcol;
        #pragma unroll
        for (int q = 0; q < 2; ++q) {
            int k = kc + zcol + q*4;
            float4 v;
            if (k + 3 < kend) v = *reinterpret_cast<const float4*>(zsrc + q*4);
            else {
                v.x = (k+0 < kend) ? zsrc[q*4+0] : 0.f;
                v.y = (k+1 < kend) ? zsrc[q*4+1] : 0.f;
                v.z = (k+2 < kend) ? zsrc[q*4+2] : 0.f;
                v.w = (k+3 < kend) ? zsrc[q*4+3] : 0.f;
            }
            *reinterpret_cast<float4*>(&zs[zrow*36 + zcol + q*4]) = v;
        }
        // stage W1 tile (32 k x 64 j)
        {
            int k = kc + wrow;
            const float* wsrc = W1 + (size_t)k*HH1 + jt*64 + wcol;
            #pragma unroll
            for (int q = 0; q < 2; ++q) {
                float4 v;
                if (k < kend) v = *reinterpret_cast<const float4*>(wsrc + q*4);
                else v = float4{0.f,0.f,0.f,0.f};
                *reinterpret_cast<float4*>(&ws[wrow*68 + wcol + q*4]) = v;
            }
        }
        __syncthreads();
        #pragma unroll
        for (int kk = 0; kk < 32; ++kk) {
            float4 w4 = *reinterpret_cast<const float4*>(&ws[kk*68 + tj*4]);
            float zv[4], wv[4] = {w4.x, w4.y, w4.z, w4.w};
            #pragma unroll
            for (int ib = 0; ib < 4; ++ib) zv[ib] = zs[(tb*4+ib)*36 + kk];
            #pragma unroll
            for (int ib = 0; ib < 4; ++ib)
                #pragma unroll
                for (int ij = 0; ij < 4; ++ij)
                    acc[ib][ij] = fmaf(zv[ib], wv[ij], acc[ib][ij]);
        }
        __syncthreads();
    }
    #pragma unroll
    for (int ib = 0; ib < 4; ++ib) {
        int row = bt*64 + tb*4 + ib;
        #pragma unroll
        for (int ij = 0; ij < 4; ++ij)
            unsafeAtomicAdd(&out1_raw[row*HH1 + jt*64 + tj*4 + ij], acc[ib][ij]);
    }
}

// ------------- tail: bn-relu -> FC2 -> bn-relu -> head dot -> out[b] -------------
__global__ __launch_bounds__(256)
void k_tail(const float* __restrict__ out1_raw,
            const float* __restrict__ fc_b1, const float* __restrict__ fbn1_g,
            const float* __restrict__ fbn1_b,
            const float* __restrict__ W2, const float* __restrict__ fc_b2,
            const float* __restrict__ fbn2_g, const float* __restrict__ fbn2_b,
            const float* __restrict__ fc1_w, const float* __restrict__ fc1_b,
            float* __restrict__ out)
{
    __shared__ float o1s[HH1];
    const int b = blockIdx.x, t = threadIdx.x;
    float raw = out1_raw[b*HH1 + t] + fc_b1[t];
    o1s[t] = fmaxf(raw * (BN_SCALE * fbn1_g[t]) + fbn1_b[t], 0.f);
    __syncthreads();
    if (t < HH2) {
        float acc = fc_b2[t];
        #pragma unroll 4
        for (int j = 0; j < HH1; ++j) acc = fmaf(o1s[j], W2[j*HH2 + t], acc);
        float v2 = fmaxf(acc * (BN_SCALE * fbn2_g[t]) + fbn2_b[t], 0.f);
        float c = v2 * fc1_w[t];
        #pragma unroll
        for (int off = 32; off; off >>= 1) c += __shfl_down(c, off);
        if (t == 0) out[b] = c + fc1_b[0];
    }
}

extern "C" void kernel_launch(void* const* d_in, const int* in_sizes, int n_in,
                              void* d_out, int out_size, void* d_ws, size_t ws_size,
                              hipStream_t stream)
{
    const float* x      = (const float*)d_in[0];
    const int*   ei     = (const int*)  d_in[1];
    const float* ew     = (const float*)d_in[2];
    const float* w_root = (const float*)d_in[3];
    const float* w_rel  = (const float*)d_in[4];
    const float* b_rel  = (const float*)d_in[5];
    const float* ln_g   = (const float*)d_in[6];
    const float* ln_b   = (const float*)d_in[7];
    const float* gc1_w  = (const float*)d_in[8];
    const float* gc1_b  = (const float*)d_in[9];
    const float* bn1_g  = (const float*)d_in[10];
    const float* bn1_b  = (const float*)d_in[11];
    const float* gc2_w  = (const float*)d_in[12];
    const float* gc2_b  = (const float*)d_in[13];
    const float* bn2_g  = (const float*)d_in[14];
    const float* bn2_b  = (const float*)d_in[15];
    const float* fc_w1  = (const float*)d_in[16];
    const float* fc_b1  = (const float*)d_in[17];
    const float* fbn1_g = (const float*)d_in[18];
    const float* fbn1_b = (const float*)d_in[19];
    const float* fc_w2  = (const float*)d_in[20];
    const float* fc_b2  = (const float*)d_in[21];
    const float* fbn2_g = (const float*)d_in[22];
    const float* fbn2_b = (const float*)d_in[23];
    const float* fc1_w  = (const float*)d_in[24];
    const float* fc1_b  = (const float*)d_in[25];
    float* out = (float*)d_out;

    // workspace layout (all offsets multiples of 256B)
    char* ws = (char*)d_ws;
    float* agg      = (float*)(ws);                         // B*N   = 564992 f
    float* zbuf     = (float*)(ws + 2259968);               // B*K1  = 2259968 f
    float* out1_raw = (float*)(ws + 2259968 + 9039872);     // 256*256 f

    hipMemsetAsync(agg,      0, (size_t)BB*NN*sizeof(float),  stream);
    hipMemsetAsync(out1_raw, 0, (size_t)BB*HH1*sizeof(float), stream);

    k_edge<<<EE/4/256, 256, 0, stream>>>(ei, ei + EE, ew, x, agg);
    k_sample<<<BB, 256, 0, stream>>>(x, agg, w_root, w_rel, b_rel, ln_g, ln_b,
                                     gc1_w, gc1_b, bn1_g, bn1_b,
                                     gc2_w, gc2_b, bn2_g, bn2_b, zbuf);
    k_fc1<<<dim3(4,4,31), 256, 0, stream>>>(zbuf, fc_w1, out1_raw);
    k_tail<<<BB, 256, 0, stream>>>(out1_raw, fc_b1, fbn1_g, fbn1_b,
                                   fc_w2, fc_b2, fbn2_g, fbn2_b,
                                   fc1_w, fc1_b, out);
}

// Round 2
// 561.177 us; speedup vs baseline: 1.6214x; 1.6214x over previous
//
#include <hip/hip_runtime.h>
#include <hip/hip_bf16.h>

#define BB   256
#define NN   2207
#define MM   16
#define EE   16777216
#define CC1  12
#define CC2  4
#define HH1  256
#define HH2  64
#define KK1  (CC2*NN)          /* 8828 */
#define LN_EPS 1e-5f
#define BN_SCALE 0.9999950000374997f   /* 1/sqrt(1+1e-5) */
#define NBK  256               /* buckets == samples */
#define CAP  68096             /* per-bucket capacity; mean 65536, sigma 256 */
#define MAGIC 1946067ull       /* ceil(2^32/2207), exact for d < 564992 */

static __device__ __forceinline__ unsigned bucket_of(int d) {
    return (unsigned)(((unsigned long long)(unsigned)d * MAGIC) >> 32);
}

// =================== PASS 1: bin edges by destination sample ===================
__global__ __launch_bounds__(256)
void k_bin(const int* __restrict__ src, const int* __restrict__ dst,
           const float* __restrict__ ew,
           uint2* __restrict__ srcw, unsigned short* __restrict__ dstl,
           unsigned int* __restrict__ glen)
{
    __shared__ unsigned int hist[NBK], basee[NBK], cur[NBK];
    const int t = threadIdx.x;
    hist[t] = 0; cur[t] = 0;
    __syncthreads();
    const int i40 = blockIdx.x * 4096;            // int4 index base; 16384 edges/block
    #pragma unroll 4
    for (int q = 0; q < 16; ++q) {
        int4 d4 = reinterpret_cast<const int4*>(dst)[i40 + q*256 + t];
        atomicAdd(&hist[bucket_of(d4.x)], 1u);
        atomicAdd(&hist[bucket_of(d4.y)], 1u);
        atomicAdd(&hist[bucket_of(d4.z)], 1u);
        atomicAdd(&hist[bucket_of(d4.w)], 1u);
    }
    __syncthreads();
    {   // one global reserve atomic per bucket, address-staggered across blocks
        int j = (t + (blockIdx.x << 3)) & (NBK - 1);
        basee[j] = atomicAdd(&glen[j], hist[j]);
    }
    __syncthreads();
    #define BIN1(S,D,W) { \
        unsigned b_ = bucket_of(D); \
        unsigned p_ = basee[b_] + atomicAdd(&cur[b_], 1u); \
        if (p_ < CAP) { \
            srcw[(size_t)b_*CAP + p_] = make_uint2((unsigned)(S), __float_as_uint(W)); \
            dstl[(size_t)b_*CAP + p_] = (unsigned short)((D) - (int)b_*NN); \
        } }
    for (int q = 0; q < 16; ++q) {
        int i4 = i40 + q*256 + t;
        int4   s4 = reinterpret_cast<const int4*>(src)[i4];
        int4   d4 = reinterpret_cast<const int4*>(dst)[i4];   // L2-hot re-read
        float4 w4 = reinterpret_cast<const float4*>(ew)[i4];
        BIN1(s4.x, d4.x, w4.x);
        BIN1(s4.y, d4.y, w4.y);
        BIN1(s4.z, d4.z, w4.z);
        BIN1(s4.w, d4.w, w4.w);
    }
    #undef BIN1
}

// ====== PASS 2 fused: LDS scatter-accumulate + relu/LN/conv1/bn/conv2/bn ======
__global__ __launch_bounds__(512)
void k_sample_fused(const float* __restrict__ x,
              const uint2* __restrict__ srcw, const unsigned short* __restrict__ dstl,
              const unsigned int* __restrict__ glen,
              const float* __restrict__ w_root, const float* __restrict__ w_rel,
              const float* __restrict__ b_rel,
              const float* __restrict__ ln_g, const float* __restrict__ ln_b,
              const float* __restrict__ gc1_w, const float* __restrict__ gc1_b,
              const float* __restrict__ bn1_g, const float* __restrict__ bn1_b,
              const float* __restrict__ gc2_w, const float* __restrict__ gc2_b,
              const float* __restrict__ bn2_g, const float* __restrict__ bn2_b,
              float* __restrict__ z)
{
    __shared__ float xs[NN], acc[NN];
    __shared__ float gw1[CC1*MM], gb1[CC1], sb1[CC1], tb1[CC1];
    __shared__ float gw2[CC2*CC1], gb2[CC2], sb2[CC2], tb2[CC2];
    __shared__ float redS[8], redQ[8];
    __shared__ float s_mu, s_rs;

    const int b = blockIdx.x, t = threadIdx.x;
    const float* xb = x + b*NN;
    for (int n = t; n < NN; n += 512) { xs[n] = xb[n]; acc[n] = 0.f; }
    if (t < CC1*MM) gw1[t] = gc1_w[t];
    if (t >= 192 && t < 192+CC1) { int o = t-192; gb1[o]=gc1_b[o]; sb1[o]=BN_SCALE*bn1_g[o]; tb1[o]=bn1_b[o]; }
    if (t >= 208 && t < 208+CC2*CC1) gw2[t-208] = gc2_w[t-208];
    if (t >= 240 && t < 240+CC2) { int p=t-240; gb2[p]=gc2_b[p]; sb2[p]=BN_SCALE*bn2_g[p]; tb2[p]=bn2_b[p]; }

    float wr[MM], br[MM], wo[MM];
    #pragma unroll
    for (int m = 0; m < MM; ++m) { wr[m]=w_rel[m]; br[m]=b_rel[m]; wo[m]=w_root[m]; }
    __syncthreads();

    // replay this sample's bucket with LDS atomics
    const unsigned len = min(glen[b], (unsigned)CAP);
    const uint2* sp = srcw + (size_t)b*CAP;
    const unsigned short* dp = dstl + (size_t)b*CAP;
    for (unsigned e = t; e < len; e += 512) {
        uint2 sw = sp[e];
        int nl = dp[e];
        atomicAdd(&acc[nl], x[sw.x] * __uint_as_float(sw.y));
    }
    __syncthreads();

    // LN statistics over (N, M)
    float S = 0.f, Q = 0.f;
    for (int n = t; n < NN; n += 512) {
        float a = acc[n], xv = xs[n];
        #pragma unroll
        for (int m = 0; m < MM; ++m) {
            float h = fmaxf(fmaf(a, wr[m], fmaf(xv, wo[m], br[m])), 0.f);
            S += h; Q += h*h;
        }
    }
    #pragma unroll
    for (int off = 32; off; off >>= 1) { S += __shfl_down(S, off); Q += __shfl_down(Q, off); }
    if ((t & 63) == 0) { redS[t>>6] = S; redQ[t>>6] = Q; }
    __syncthreads();
    if (t == 0) {
        float SS = 0.f, QQ = 0.f;
        #pragma unroll
        for (int i = 0; i < 8; ++i) { SS += redS[i]; QQ += redQ[i]; }
        const float inv = 1.f / (float)(NN*MM);
        float mu = SS * inv;
        float var = QQ * inv - mu*mu;
        s_mu = mu; s_rs = rsqrtf(var + LN_EPS);
    }
    __syncthreads();
    const float mu = s_mu, rs = s_rs;

    float* zb = z + (size_t)b * KK1;
    for (int n = t; n < NN; n += 512) {
        float a = acc[n], xv = xs[n];
        float hn[MM];
        const float4* g4  = reinterpret_cast<const float4*>(ln_g + n*MM);
        const float4* be4 = reinterpret_cast<const float4*>(ln_b + n*MM);
        #pragma unroll
        for (int q = 0; q < 4; ++q) {
            float4 g = g4[q], be = be4[q];
            float gg[4]  = {g.x, g.y, g.z, g.w};
            float bb_[4] = {be.x, be.y, be.z, be.w};
            #pragma unroll
            for (int j = 0; j < 4; ++j) {
                int m = q*4 + j;
                float h = fmaxf(fmaf(a, wr[m], fmaf(xv, wo[m], br[m])), 0.f);
                hn[m] = (h - mu) * rs * gg[j] + bb_[j];
            }
        }
        float y1[CC1];
        #pragma unroll
        for (int o = 0; o < CC1; ++o) {
            float a1 = gb1[o];
            #pragma unroll
            for (int m = 0; m < MM; ++m) a1 = fmaf(gw1[o*MM+m], hn[m], a1);
            y1[o] = fmaxf(a1, 0.f) * sb1[o] + tb1[o];
        }
        #pragma unroll
        for (int p = 0; p < CC2; ++p) {
            float a2 = gb2[p];
            #pragma unroll
            for (int o = 0; o < CC1; ++o) a2 = fmaf(gw2[p*CC1+o], y1[o], a2);
            zb[p*NN + n] = fmaxf(a2, 0.f) * sb2[p] + tb2[p];
        }
    }
}

// ------------- FC1 GEMM: split-K partials (no atomics) -------------
#define GK_CHUNK 288   /* grid.z = 31; 31*288 = 8928 >= 8828 */
__global__ __launch_bounds__(256)
void k_fc1_part(const float* __restrict__ z, const float* __restrict__ W1,
                float* __restrict__ out1_part)
{
    __shared__ float zs[64*36];
    __shared__ float ws_[32*68];
    const int bt = blockIdx.x, jt = blockIdx.y, ks = blockIdx.z;
    const int t = threadIdx.x;
    const int tb = t >> 4, tj = t & 15;
    const int k0 = ks * GK_CHUNK;
    const int kend = min(k0 + GK_CHUNK, KK1);
    float acc[4][4] = {};
    const int zrow = t >> 2, zcol = (t & 3) * 8;
    const int wrow = t >> 3, wcol = (t & 7) * 8;

    for (int kc = k0; kc < kend; kc += 32) {
        const float* zsrc = z + (size_t)(bt*64 + zrow)*KK1 + kc + zcol;
        #pragma unroll
        for (int q = 0; q < 2; ++q) {
            int k = kc + zcol + q*4;
            float4 v;
            if (k + 3 < kend) v = *reinterpret_cast<const float4*>(zsrc + q*4);
            else {
                v.x = (k+0 < kend) ? zsrc[q*4+0] : 0.f;
                v.y = (k+1 < kend) ? zsrc[q*4+1] : 0.f;
                v.z = (k+2 < kend) ? zsrc[q*4+2] : 0.f;
                v.w = (k+3 < kend) ? zsrc[q*4+3] : 0.f;
            }
            *reinterpret_cast<float4*>(&zs[zrow*36 + zcol + q*4]) = v;
        }
        {
            int k = kc + wrow;
            const float* wsrc = W1 + (size_t)k*HH1 + jt*64 + wcol;
            #pragma unroll
            for (int q = 0; q < 2; ++q) {
                float4 v;
                if (k < kend) v = *reinterpret_cast<const float4*>(wsrc + q*4);
                else v = float4{0.f,0.f,0.f,0.f};
                *reinterpret_cast<float4*>(&ws_[wrow*68 + wcol + q*4]) = v;
            }
        }
        __syncthreads();
        #pragma unroll
        for (int kk = 0; kk < 32; ++kk) {
            float4 w4 = *reinterpret_cast<const float4*>(&ws_[kk*68 + tj*4]);
            float zv[4], wv[4] = {w4.x, w4.y, w4.z, w4.w};
            #pragma unroll
            for (int ib = 0; ib < 4; ++ib) zv[ib] = zs[(tb*4+ib)*36 + kk];
            #pragma unroll
            for (int ib = 0; ib < 4; ++ib)
                #pragma unroll
                for (int ij = 0; ij < 4; ++ij)
                    acc[ib][ij] = fmaf(zv[ib], wv[ij], acc[ib][ij]);
        }
        __syncthreads();
    }
    #pragma unroll
    for (int ib = 0; ib < 4; ++ib) {
        int row = bt*64 + tb*4 + ib;
        float4 v = make_float4(acc[ib][0], acc[ib][1], acc[ib][2], acc[ib][3]);
        *reinterpret_cast<float4*>(
            &out1_part[((size_t)ks*256 + row)*HH1 + jt*64 + tj*4]) = v;
    }
}

// ------------- tail: sum partials -> bn-relu -> FC2 -> bn-relu -> dot -------------
__global__ __launch_bounds__(256)
void k_tail_part(const float* __restrict__ out1_part,
            const float* __restrict__ fc_b1, const float* __restrict__ fbn1_g,
            const float* __restrict__ fbn1_b,
            const float* __restrict__ W2, const float* __restrict__ fc_b2,
            const float* __restrict__ fbn2_g, const float* __restrict__ fbn2_b,
            const float* __restrict__ fc1_w, const float* __restrict__ fc1_b,
            float* __restrict__ out)
{
    __shared__ float o1s[HH1];
    const int b = blockIdx.x, t = threadIdx.x;
    float raw = fc_b1[t];
    #pragma unroll 4
    for (int ks = 0; ks < 31; ++ks)
        raw += out1_part[((size_t)ks*256 + b)*HH1 + t];
    o1s[t] = fmaxf(raw * (BN_SCALE * fbn1_g[t]) + fbn1_b[t], 0.f);
    __syncthreads();
    if (t < HH2) {
        float acc = fc_b2[t];
        #pragma unroll 4
        for (int j = 0; j < HH1; ++j) acc = fmaf(o1s[j], W2[j*HH2 + t], acc);
        float v2 = fmaxf(acc * (BN_SCALE * fbn2_g[t]) + fbn2_b[t], 0.f);
        float c = v2 * fc1_w[t];
        #pragma unroll
        for (int off = 32; off; off >>= 1) c += __shfl_down(c, off);
        if (t == 0) out[b] = c + fc1_b[0];
    }
}

// =================== fallback path (round-1, proven; used if ws too small) ===================
__global__ __launch_bounds__(256)
void k_edge(const int* __restrict__ src, const int* __restrict__ dst,
            const float* __restrict__ ew, const float* __restrict__ x,
            float* __restrict__ agg)
{
    int i = blockIdx.x * 256 + threadIdx.x;
    const int4   s4 = reinterpret_cast<const int4*>(src)[i];
    const int4   d4 = reinterpret_cast<const int4*>(dst)[i];
    const float4 w4 = reinterpret_cast<const float4*>(ew)[i];
    unsafeAtomicAdd(&agg[d4.x], x[s4.x] * w4.x);
    unsafeAtomicAdd(&agg[d4.y], x[s4.y] * w4.y);
    unsafeAtomicAdd(&agg[d4.z], x[s4.z] * w4.z);
    unsafeAtomicAdd(&agg[d4.w], x[s4.w] * w4.w);
}

__global__ __launch_bounds__(256)
void k_sample(const float* __restrict__ x, const float* __restrict__ agg,
              const float* __restrict__ w_root, const float* __restrict__ w_rel,
              const float* __restrict__ b_rel,
              const float* __restrict__ ln_g, const float* __restrict__ ln_b,
              const float* __restrict__ gc1_w, const float* __restrict__ gc1_b,
              const float* __restrict__ bn1_g, const float* __restrict__ bn1_b,
              const float* __restrict__ gc2_w, const float* __restrict__ gc2_b,
              const float* __restrict__ bn2_g, const float* __restrict__ bn2_b,
              float* __restrict__ z)
{
    __shared__ float xs[NN], as[NN];
    __shared__ float gw1[CC1*MM], gb1[CC1], sb1[CC1], tb1[CC1];
    __shared__ float gw2[CC2*CC1], gb2[CC2], sb2[CC2], tb2[CC2];
    __shared__ float redS[4], redQ[4];
    __shared__ float s_mu, s_rs;

    const int b = blockIdx.x, t = threadIdx.x;
    const float* xb = x + b*NN;
    const float* ab = agg + b*NN;
    for (int n = t; n < NN; n += 256) { xs[n] = xb[n]; as[n] = ab[n]; }
    if (t < CC1*MM) gw1[t] = gc1_w[t];
    if (t >= 192 && t < 192+CC1) { int o = t-192; gb1[o]=gc1_b[o]; sb1[o]=BN_SCALE*bn1_g[o]; tb1[o]=bn1_b[o]; }
    if (t >= 208 && t < 208+CC2*CC1) gw2[t-208] = gc2_w[t-208];
    if (t >= 240 && t < 240+CC2) { int p=t-240; gb2[p]=gc2_b[p]; sb2[p]=BN_SCALE*bn2_g[p]; tb2[p]=bn2_b[p]; }

    float wr[MM], br[MM], wo[MM];
    #pragma unroll
    for (int m = 0; m < MM; ++m) { wr[m]=w_rel[m]; br[m]=b_rel[m]; wo[m]=w_root[m]; }
    __syncthreads();

    float S = 0.f, Q = 0.f;
    for (int n = t; n < NN; n += 256) {
        float a = as[n], xv = xs[n];
        #pragma unroll
        for (int m = 0; m < MM; ++m) {
            float h = fmaxf(fmaf(a, wr[m], fmaf(xv, wo[m], br[m])), 0.f);
            S += h; Q += h*h;
        }
    }
    #pragma unroll
    for (int off = 32; off; off >>= 1) { S += __shfl_down(S, off); Q += __shfl_down(Q, off); }
    if ((t & 63) == 0) { redS[t>>6] = S; redQ[t>>6] = Q; }
    __syncthreads();
    if (t == 0) {
        float SS = redS[0]+redS[1]+redS[2]+redS[3];
        float QQ = redQ[0]+redQ[1]+redQ[2]+redQ[3];
        const float inv = 1.f / (float)(NN*MM);
        float mu = SS * inv;
        float var = QQ * inv - mu*mu;
        s_mu = mu; s_rs = rsqrtf(var + LN_EPS);
    }
    __syncthreads();
    const float mu = s_mu, rs = s_rs;

    float* zb = z + (size_t)b * KK1;
    for (int n = t; n < NN; n += 256) {
        float a = as[n], xv = xs[n];
        float hn[MM];
        const float4* g4  = reinterpret_cast<const float4*>(ln_g + n*MM);
        const float4* be4 = reinterpret_cast<const float4*>(ln_b + n*MM);
        #pragma unroll
        for (int q = 0; q < 4; ++q) {
            float4 g = g4[q], be = be4[q];
            float gg[4]  = {g.x, g.y, g.z, g.w};
            float bb_[4] = {be.x, be.y, be.z, be.w};
            #pragma unroll
            for (int j = 0; j < 4; ++j) {
                int m = q*4 + j;
                float h = fmaxf(fmaf(a, wr[m], fmaf(xv, wo[m], br[m])), 0.f);
                hn[m] = (h - mu) * rs * gg[j] + bb_[j];
            }
        }
        float y1[CC1];
        #pragma unroll
        for (int o = 0; o < CC1; ++o) {
            float a1 = gb1[o];
            #pragma unroll
            for (int m = 0; m < MM; ++m) a1 = fmaf(gw1[o*MM+m], hn[m], a1);
            y1[o] = fmaxf(a1, 0.f) * sb1[o] + tb1[o];
        }
        #pragma unroll
        for (int p = 0; p < CC2; ++p) {
            float a2 = gb2[p];
            #pragma unroll
            for (int o = 0; o < CC1; ++o) a2 = fmaf(gw2[p*CC1+o], y1[o], a2);
            zb[p*NN + n] = fmaxf(a2, 0.f) * sb2[p] + tb2[p];
        }
    }
}

__global__ __launch_bounds__(256)
void k_fc1(const float* __restrict__ z, const float* __restrict__ W1,
           float* __restrict__ out1_raw)
{
    __shared__ float zs[64*36];
    __shared__ float ws_[32*68];
    const int bt = blockIdx.x, jt = blockIdx.y, ks = blockIdx.z;
    const int t = threadIdx.x;
    const int tb = t >> 4, tj = t & 15;
    const int k0 = ks * GK_CHUNK;
    const int kend = min(k0 + GK_CHUNK, KK1);
    float acc[4][4] = {};
    const int zrow = t >> 2, zcol = (t & 3) * 8;
    const int wrow = t >> 3, wcol = (t & 7) * 8;

    for (int kc = k0; kc < kend; kc += 32) {
        const float* zsrc = z + (size_t)(bt*64 + zrow)*KK1 + kc + zcol;
        #pragma unroll
        for (int q = 0; q < 2; ++q) {
            int k = kc + zcol + q*4;
            float4 v;
            if (k + 3 < kend) v = *reinterpret_cast<const float4*>(zsrc + q*4);
            else {
                v.x = (k+0 < kend) ? zsrc[q*4+0] : 0.f;
                v.y = (k+1 < kend) ? zsrc[q*4+1] : 0.f;
                v.z = (k+2 < kend) ? zsrc[q*4+2] : 0.f;
                v.w = (k+3 < kend) ? zsrc[q*4+3] : 0.f;
            }
            *reinterpret_cast<float4*>(&zs[zrow*36 + zcol + q*4]) = v;
        }
        {
            int k = kc + wrow;
            const float* wsrc = W1 + (size_t)k*HH1 + jt*64 + wcol;
            #pragma unroll
            for (int q = 0; q < 2; ++q) {
                float4 v;
                if (k < kend) v = *reinterpret_cast<const float4*>(wsrc + q*4);
                else v = float4{0.f,0.f,0.f,0.f};
                *reinterpret_cast<float4*>(&ws_[wrow*68 + wcol + q*4]) = v;
            }
        }
        __syncthreads();
        #pragma unroll
        for (int kk = 0; kk < 32; ++kk) {
            float4 w4 = *reinterpret_cast<const float4*>(&ws_[kk*68 + tj*4]);
            float zv[4], wv[4] = {w4.x, w4.y, w4.z, w4.w};
            #pragma unroll
            for (int ib = 0; ib < 4; ++ib) zv[ib] = zs[(tb*4+ib)*36 + kk];
            #pragma unroll
            for (int ib = 0; ib < 4; ++ib)
                #pragma unroll
                for (int ij = 0; ij < 4; ++ij)
                    acc[ib][ij] = fmaf(zv[ib], wv[ij], acc[ib][ij]);
        }
        __syncthreads();
    }
    #pragma unroll
    for (int ib = 0; ib < 4; ++ib) {
        int row = bt*64 + tb*4 + ib;
        #pragma unroll
        for (int ij = 0; ij < 4; ++ij)
            unsafeAtomicAdd(&out1_raw[row*HH1 + jt*64 + tj*4 + ij], acc[ib][ij]);
    }
}

__global__ __launch_bounds__(256)
void k_tail(const float* __restrict__ out1_raw,
            const float* __restrict__ fc_b1, const float* __restrict__ fbn1_g,
            const float* __restrict__ fbn1_b,
            const float* __restrict__ W2, const float* __restrict__ fc_b2,
            const float* __restrict__ fbn2_g, const float* __restrict__ fbn2_b,
            const float* __restrict__ fc1_w, const float* __restrict__ fc1_b,
            float* __restrict__ out)
{
    __shared__ float o1s[HH1];
    const int b = blockIdx.x, t = threadIdx.x;
    float raw = out1_raw[b*HH1 + t] + fc_b1[t];
    o1s[t] = fmaxf(raw * (BN_SCALE * fbn1_g[t]) + fbn1_b[t], 0.f);
    __syncthreads();
    if (t < HH2) {
        float acc = fc_b2[t];
        #pragma unroll 4
        for (int j = 0; j < HH1; ++j) acc = fmaf(o1s[j], W2[j*HH2 + t], acc);
        float v2 = fmaxf(acc * (BN_SCALE * fbn2_g[t]) + fbn2_b[t], 0.f);
        float c = v2 * fc1_w[t];
        #pragma unroll
        for (int off = 32; off; off >>= 1) c += __shfl_down(c, off);
        if (t == 0) out[b] = c + fc1_b[0];
    }
}

extern "C" void kernel_launch(void* const* d_in, const int* in_sizes, int n_in,
                              void* d_out, int out_size, void* d_ws, size_t ws_size,
                              hipStream_t stream)
{
    const float* x      = (const float*)d_in[0];
    const int*   ei     = (const int*)  d_in[1];
    const float* ew     = (const float*)d_in[2];
    const float* w_root = (const float*)d_in[3];
    const float* w_rel  = (const float*)d_in[4];
    const float* b_rel  = (const float*)d_in[5];
    const float* ln_g   = (const float*)d_in[6];
    const float* ln_b   = (const float*)d_in[7];
    const float* gc1_w  = (const float*)d_in[8];
    const float* gc1_b  = (const float*)d_in[9];
    const float* bn1_g  = (const float*)d_in[10];
    const float* bn1_b  = (const float*)d_in[11];
    const float* gc2_w  = (const float*)d_in[12];
    const float* gc2_b  = (const float*)d_in[13];
    const float* bn2_g  = (const float*)d_in[14];
    const float* bn2_b  = (const float*)d_in[15];
    const float* fc_w1  = (const float*)d_in[16];
    const float* fc_b1  = (const float*)d_in[17];
    const float* fbn1_g = (const float*)d_in[18];
    const float* fbn1_b = (const float*)d_in[19];
    const float* fc_w2  = (const float*)d_in[20];
    const float* fc_b2  = (const float*)d_in[21];
    const float* fbn2_g = (const float*)d_in[22];
    const float* fbn2_b = (const float*)d_in[23];
    const float* fc1_w  = (const float*)d_in[24];
    const float* fc1_b  = (const float*)d_in[25];
    float* out = (float*)d_out;

    char* ws = (char*)d_ws;
    // primary layout
    const size_t off_srcw = 0;                                   // 256*CAP*8  = 139,460,608
    const size_t off_dstl = off_srcw + (size_t)NBK*CAP*8;        // +34,865,152
    const size_t off_glen = off_dstl + (size_t)NBK*CAP*2;        // +4096
    const size_t off_zbuf = off_glen + 4096;                     // +9,039,872
    const size_t off_op   = off_zbuf + (size_t)BB*KK1*4;         // +31*65536*4
    const size_t need     = off_op + (size_t)31*HH1*256*4;

    if (ws_size >= need) {
        uint2*          srcw = (uint2*)(ws + off_srcw);
        unsigned short* dstl = (unsigned short*)(ws + off_dstl);
        unsigned int*   glen = (unsigned int*)(ws + off_glen);
        float*          zbuf = (float*)(ws + off_zbuf);
        float*          o1p  = (float*)(ws + off_op);

        hipMemsetAsync(glen, 0, 4096, stream);
        k_bin<<<EE/16384, 256, 0, stream>>>(ei, ei + EE, ew, srcw, dstl, glen);
        k_sample_fused<<<BB, 512, 0, stream>>>(x, srcw, dstl, glen,
                                         w_root, w_rel, b_rel, ln_g, ln_b,
                                         gc1_w, gc1_b, bn1_g, bn1_b,
                                         gc2_w, gc2_b, bn2_g, bn2_b, zbuf);
        k_fc1_part<<<dim3(4,4,31), 256, 0, stream>>>(zbuf, fc_w1, o1p);
        k_tail_part<<<BB, 256, 0, stream>>>(o1p, fc_b1, fbn1_g, fbn1_b,
                                       fc_w2, fc_b2, fbn2_g, fbn2_b,
                                       fc1_w, fc1_b, out);
    } else {
        // round-1 fallback (proven <= 11.6 MB ws)
        float* agg      = (float*)(ws);
        float* zbuf     = (float*)(ws + 2259968);
        float* out1_raw = (float*)(ws + 2259968 + 9039872);

        hipMemsetAsync(agg,      0, (size_t)BB*NN*sizeof(float),  stream);
        hipMemsetAsync(out1_raw, 0, (size_t)BB*HH1*sizeof(float), stream);

        k_edge<<<EE/4/256, 256, 0, stream>>>(ei, ei + EE, ew, x, agg);
        k_sample<<<BB, 256, 0, stream>>>(x, agg, w_root, w_rel, b_rel, ln_g, ln_b,
                                         gc1_w, gc1_b, bn1_g, bn1_b,
                                         gc2_w, gc2_b, bn2_g, bn2_b, zbuf);
        k_fc1<<<dim3(4,4,31), 256, 0, stream>>>(zbuf, fc_w1, out1_raw);
        k_tail<<<BB, 256, 0, stream>>>(out1_raw, fc_b1, fbn1_g, fbn1_b,
                                       fc_w2, fc_b2, fbn2_g, fbn2_b,
                                       fc1_w, fc1_b, out);
    }
}

// Round 3
// 352.422 us; speedup vs baseline: 2.5818x; 1.5923x over previous
//
#include <hip/hip_runtime.h>
#include <hip/hip_bf16.h>

#define BB   256
#define NN   2207
#define MM   16
#define EE   16777216
#define CC1  12
#define CC2  4
#define HH1  256
#define HH2  64
#define KK1  (CC2*NN)          /* 8828 */
#define LN_EPS 1e-5f
#define BN_SCALE 0.9999950000374997f   /* 1/sqrt(1+1e-5) */
#define NBK  256               /* buckets == samples */
#define CAP  68096             /* per-bucket capacity; mean 65536, ~10 sigma headroom */
#define MAGIC 1946067ull       /* ceil(2^32/2207), exact for d < 564992 */
#define EPB  8192              /* edges per bin block */
#define TPB  512

static __device__ __forceinline__ unsigned bucket_of(int d) {
    return (unsigned)(((unsigned long long)(unsigned)d * MAGIC) >> 32);
}

// ============ PASS 1: block-local counting sort -> coalesced bucket append ============
__global__ __launch_bounds__(TPB)
void k_bin2(const int* __restrict__ src, const int* __restrict__ dst,
            const float* __restrict__ ew, const float* __restrict__ x,
            uint2* __restrict__ pairs, unsigned int* __restrict__ glen)
{
    __shared__ uint2         pl[EPB];          // 64 KB sorted (dst_local, val) records
    __shared__ unsigned char bl[EPB];          // 8 KB bucket id per record
    __shared__ unsigned int  hist[NBK], start[NBK], cur[NBK], baseg[NBK];
    __shared__ unsigned int  wtot[4];

    const int t = threadIdx.x;
    if (t < NBK) hist[t] = 0;
    __syncthreads();

    const int i4base = blockIdx.x * (EPB/4);
    int4 dreg[4];
    #pragma unroll
    for (int q = 0; q < 4; ++q) {
        dreg[q] = reinterpret_cast<const int4*>(dst)[i4base + q*TPB + t];
        atomicAdd(&hist[bucket_of(dreg[q].x)], 1u);
        atomicAdd(&hist[bucket_of(dreg[q].y)], 1u);
        atomicAdd(&hist[bucket_of(dreg[q].z)], 1u);
        atomicAdd(&hist[bucket_of(dreg[q].w)], 1u);
    }
    __syncthreads();

    // exclusive prefix scan of hist[256] (4 waves of 64)
    if (t < NBK) {
        unsigned h = hist[t], v = h;
        #pragma unroll
        for (int off = 1; off < 64; off <<= 1) {
            unsigned u = __shfl_up(v, off);
            if ((t & 63) >= off) v += u;
        }
        start[t] = v - h;                       // exclusive within wave
        if ((t & 63) == 63) wtot[t >> 6] = v;   // wave total
    }
    __syncthreads();
    if (t < NBK) {
        const int w = t >> 6;
        unsigned wo = 0;
        if (w > 0) wo += wtot[0];
        if (w > 1) wo += wtot[1];
        if (w > 2) wo += wtot[2];
        start[t] += wo;
        cur[t] = 0;
        int j = (t + (blockIdx.x << 2)) & (NBK - 1);   // stagger reserve addresses
        baseg[j] = atomicAdd(&glen[j], hist[j]);
    }
    __syncthreads();

    // place records at sorted LDS positions (val computed here: x-gather is L2-hot)
    #define PLACE(S,D,W) { \
        unsigned b_ = bucket_of(D); \
        float v_ = x[S] * (W); \
        unsigned p_ = start[b_] + atomicAdd(&cur[b_], 1u); \
        pl[p_] = make_uint2((unsigned)((D) - (int)(b_*NN)), __float_as_uint(v_)); \
        bl[p_] = (unsigned char)b_; }
    #pragma unroll
    for (int q = 0; q < 4; ++q) {
        int i4 = i4base + q*TPB + t;
        int4   s4 = reinterpret_cast<const int4*>(src)[i4];
        float4 w4 = reinterpret_cast<const float4*>(ew)[i4];
        int4   d4 = dreg[q];
        PLACE(s4.x, d4.x, w4.x);
        PLACE(s4.y, d4.y, w4.y);
        PLACE(s4.z, d4.z, w4.z);
        PLACE(s4.w, d4.w, w4.w);
    }
    #undef PLACE
    __syncthreads();

    // coalesced flush: consecutive lanes write consecutive slots of each bucket run
    #pragma unroll
    for (int q = 0; q < EPB/TPB; ++q) {
        int i = q*TPB + t;
        unsigned j = bl[i];
        unsigned g = baseg[j] + ((unsigned)i - start[j]);
        if (g < CAP) pairs[(size_t)j*CAP + g] = pl[i];
    }
}

// ====== PASS 2 fused: LDS scatter-accumulate + relu/LN/conv1/bn/conv2/bn ======
__global__ __launch_bounds__(512)
void k_sample_fused(const float* __restrict__ x,
              const uint2* __restrict__ pairs, const unsigned int* __restrict__ glen,
              const float* __restrict__ w_root, const float* __restrict__ w_rel,
              const float* __restrict__ b_rel,
              const float* __restrict__ ln_g, const float* __restrict__ ln_b,
              const float* __restrict__ gc1_w, const float* __restrict__ gc1_b,
              const float* __restrict__ bn1_g, const float* __restrict__ bn1_b,
              const float* __restrict__ gc2_w, const float* __restrict__ gc2_b,
              const float* __restrict__ bn2_g, const float* __restrict__ bn2_b,
              float* __restrict__ z)
{
    __shared__ float xs[NN], acc[NN];
    __shared__ float gw1[CC1*MM], gb1[CC1], sb1[CC1], tb1[CC1];
    __shared__ float gw2[CC2*CC1], gb2[CC2], sb2[CC2], tb2[CC2];
    __shared__ float redS[8], redQ[8];
    __shared__ float s_mu, s_rs;

    const int b = blockIdx.x, t = threadIdx.x;
    const float* xb = x + b*NN;
    for (int n = t; n < NN; n += 512) { xs[n] = xb[n]; acc[n] = 0.f; }
    if (t < CC1*MM) gw1[t] = gc1_w[t];
    if (t >= 192 && t < 192+CC1) { int o = t-192; gb1[o]=gc1_b[o]; sb1[o]=BN_SCALE*bn1_g[o]; tb1[o]=bn1_b[o]; }
    if (t >= 208 && t < 208+CC2*CC1) gw2[t-208] = gc2_w[t-208];
    if (t >= 240 && t < 240+CC2) { int p=t-240; gb2[p]=gc2_b[p]; sb2[p]=BN_SCALE*bn2_g[p]; tb2[p]=bn2_b[p]; }

    float wr[MM], br[MM], wo[MM];
    #pragma unroll
    for (int m = 0; m < MM; ++m) { wr[m]=w_rel[m]; br[m]=b_rel[m]; wo[m]=w_root[m]; }
    __syncthreads();

    // replay this sample's bucket: pure stream + LDS atomic
    const unsigned len = min(glen[b], (unsigned)CAP);
    const uint2* pp = pairs + (size_t)b*CAP;
    for (unsigned e = t; e < len; e += 512) {
        uint2 pr = pp[e];
        atomicAdd(&acc[pr.x], __uint_as_float(pr.y));
    }
    __syncthreads();

    // LN statistics over (N, M)
    float S = 0.f, Q = 0.f;
    for (int n = t; n < NN; n += 512) {
        float a = acc[n], xv = xs[n];
        #pragma unroll
        for (int m = 0; m < MM; ++m) {
            float h = fmaxf(fmaf(a, wr[m], fmaf(xv, wo[m], br[m])), 0.f);
            S += h; Q += h*h;
        }
    }
    #pragma unroll
    for (int off = 32; off; off >>= 1) { S += __shfl_down(S, off); Q += __shfl_down(Q, off); }
    if ((t & 63) == 0) { redS[t>>6] = S; redQ[t>>6] = Q; }
    __syncthreads();
    if (t == 0) {
        float SS = 0.f, QQ = 0.f;
        #pragma unroll
        for (int i = 0; i < 8; ++i) { SS += redS[i]; QQ += redQ[i]; }
        const float inv = 1.f / (float)(NN*MM);
        float mu = SS * inv;
        float var = QQ * inv - mu*mu;
        s_mu = mu; s_rs = rsqrtf(var + LN_EPS);
    }
    __syncthreads();
    const float mu = s_mu, rs = s_rs;

    float* zb = z + (size_t)b * KK1;
    for (int n = t; n < NN; n += 512) {
        float a = acc[n], xv = xs[n];
        float hn[MM];
        const float4* g4  = reinterpret_cast<const float4*>(ln_g + n*MM);
        const float4* be4 = reinterpret_cast<const float4*>(ln_b + n*MM);
        #pragma unroll
        for (int q = 0; q < 4; ++q) {
            float4 g = g4[q], be = be4[q];
            float gg[4]  = {g.x, g.y, g.z, g.w};
            float bb_[4] = {be.x, be.y, be.z, be.w};
            #pragma unroll
            for (int j = 0; j < 4; ++j) {
                int m = q*4 + j;
                float h = fmaxf(fmaf(a, wr[m], fmaf(xv, wo[m], br[m])), 0.f);
                hn[m] = (h - mu) * rs * gg[j] + bb_[j];
            }
        }
        float y1[CC1];
        #pragma unroll
        for (int o = 0; o < CC1; ++o) {
            float a1 = gb1[o];
            #pragma unroll
            for (int m = 0; m < MM; ++m) a1 = fmaf(gw1[o*MM+m], hn[m], a1);
            y1[o] = fmaxf(a1, 0.f) * sb1[o] + tb1[o];
        }
        #pragma unroll
        for (int p = 0; p < CC2; ++p) {
            float a2 = gb2[p];
            #pragma unroll
            for (int o = 0; o < CC1; ++o) a2 = fmaf(gw2[p*CC1+o], y1[o], a2);
            zb[p*NN + n] = fmaxf(a2, 0.f) * sb2[p] + tb2[p];
        }
    }
}

// ------------- FC1 GEMM: split-K partials (no atomics) -------------
#define GK_CHUNK 288   /* grid.z = 31; 31*288 = 8928 >= 8828 */
__global__ __launch_bounds__(256)
void k_fc1_part(const float* __restrict__ z, const float* __restrict__ W1,
                float* __restrict__ out1_part)
{
    __shared__ float zs[64*36];
    __shared__ float ws_[32*68];
    const int bt = blockIdx.x, jt = blockIdx.y, ks = blockIdx.z;
    const int t = threadIdx.x;
    const int tb = t >> 4, tj = t & 15;
    const int k0 = ks * GK_CHUNK;
    const int kend = min(k0 + GK_CHUNK, KK1);
    float acc[4][4] = {};
    const int zrow = t >> 2, zcol = (t & 3) * 8;
    const int wrow = t >> 3, wcol = (t & 7) * 8;

    for (int kc = k0; kc < kend; kc += 32) {
        const float* zsrc = z + (size_t)(bt*64 + zrow)*KK1 + kc + zcol;
        #pragma unroll
        for (int q = 0; q < 2; ++q) {
            int k = kc + zcol + q*4;
            float4 v;
            if (k + 3 < kend) v = *reinterpret_cast<const float4*>(zsrc + q*4);
            else {
                v.x = (k+0 < kend) ? zsrc[q*4+0] : 0.f;
                v.y = (k+1 < kend) ? zsrc[q*4+1] : 0.f;
                v.z = (k+2 < kend) ? zsrc[q*4+2] : 0.f;
                v.w = (k+3 < kend) ? zsrc[q*4+3] : 0.f;
            }
            *reinterpret_cast<float4*>(&zs[zrow*36 + zcol + q*4]) = v;
        }
        {
            int k = kc + wrow;
            const float* wsrc = W1 + (size_t)k*HH1 + jt*64 + wcol;
            #pragma unroll
            for (int q = 0; q < 2; ++q) {
                float4 v;
                if (k < kend) v = *reinterpret_cast<const float4*>(wsrc + q*4);
                else v = float4{0.f,0.f,0.f,0.f};
                *reinterpret_cast<float4*>(&ws_[wrow*68 + wcol + q*4]) = v;
            }
        }
        __syncthreads();
        #pragma unroll
        for (int kk = 0; kk < 32; ++kk) {
            float4 w4 = *reinterpret_cast<const float4*>(&ws_[kk*68 + tj*4]);
            float zv[4], wv[4] = {w4.x, w4.y, w4.z, w4.w};
            #pragma unroll
            for (int ib = 0; ib < 4; ++ib) zv[ib] = zs[(tb*4+ib)*36 + kk];
            #pragma unroll
            for (int ib = 0; ib < 4; ++ib)
                #pragma unroll
                for (int ij = 0; ij < 4; ++ij)
                    acc[ib][ij] = fmaf(zv[ib], wv[ij], acc[ib][ij]);
        }
        __syncthreads();
    }
    #pragma unroll
    for (int ib = 0; ib < 4; ++ib) {
        int row = bt*64 + tb*4 + ib;
        float4 v = make_float4(acc[ib][0], acc[ib][1], acc[ib][2], acc[ib][3]);
        *reinterpret_cast<float4*>(
            &out1_part[((size_t)ks*256 + row)*HH1 + jt*64 + tj*4]) = v;
    }
}

// ------------- tail: sum partials -> bn-relu -> FC2 -> bn-relu -> dot -------------
__global__ __launch_bounds__(256)
void k_tail_part(const float* __restrict__ out1_part,
            const float* __restrict__ fc_b1, const float* __restrict__ fbn1_g,
            const float* __restrict__ fbn1_b,
            const float* __restrict__ W2, const float* __restrict__ fc_b2,
            const float* __restrict__ fbn2_g, const float* __restrict__ fbn2_b,
            const float* __restrict__ fc1_w, const float* __restrict__ fc1_b,
            float* __restrict__ out)
{
    __shared__ float o1s[HH1];
    const int b = blockIdx.x, t = threadIdx.x;
    float raw = fc_b1[t];
    #pragma unroll 4
    for (int ks = 0; ks < 31; ++ks)
        raw += out1_part[((size_t)ks*256 + b)*HH1 + t];
    o1s[t] = fmaxf(raw * (BN_SCALE * fbn1_g[t]) + fbn1_b[t], 0.f);
    __syncthreads();
    if (t < HH2) {
        float acc = fc_b2[t];
        #pragma unroll 4
        for (int j = 0; j < HH1; ++j) acc = fmaf(o1s[j], W2[j*HH2 + t], acc);
        float v2 = fmaxf(acc * (BN_SCALE * fbn2_g[t]) + fbn2_b[t], 0.f);
        float c = v2 * fc1_w[t];
        #pragma unroll
        for (int off = 32; off; off >>= 1) c += __shfl_down(c, off);
        if (t == 0) out[b] = c + fc1_b[0];
    }
}

// =================== fallback path (round-1, proven; used if ws too small) ===================
__global__ __launch_bounds__(256)
void k_edge(const int* __restrict__ src, const int* __restrict__ dst,
            const float* __restrict__ ew, const float* __restrict__ x,
            float* __restrict__ agg)
{
    int i = blockIdx.x * 256 + threadIdx.x;
    const int4   s4 = reinterpret_cast<const int4*>(src)[i];
    const int4   d4 = reinterpret_cast<const int4*>(dst)[i];
    const float4 w4 = reinterpret_cast<const float4*>(ew)[i];
    unsafeAtomicAdd(&agg[d4.x], x[s4.x] * w4.x);
    unsafeAtomicAdd(&agg[d4.y], x[s4.y] * w4.y);
    unsafeAtomicAdd(&agg[d4.z], x[s4.z] * w4.z);
    unsafeAtomicAdd(&agg[d4.w], x[s4.w] * w4.w);
}

__global__ __launch_bounds__(256)
void k_sample(const float* __restrict__ x, const float* __restrict__ agg,
              const float* __restrict__ w_root, const float* __restrict__ w_rel,
              const float* __restrict__ b_rel,
              const float* __restrict__ ln_g, const float* __restrict__ ln_b,
              const float* __restrict__ gc1_w, const float* __restrict__ gc1_b,
              const float* __restrict__ bn1_g, const float* __restrict__ bn1_b,
              const float* __restrict__ gc2_w, const float* __restrict__ gc2_b,
              const float* __restrict__ bn2_g, const float* __restrict__ bn2_b,
              float* __restrict__ z)
{
    __shared__ float xs[NN], as[NN];
    __shared__ float gw1[CC1*MM], gb1[CC1], sb1[CC1], tb1[CC1];
    __shared__ float gw2[CC2*CC1], gb2[CC2], sb2[CC2], tb2[CC2];
    __shared__ float redS[4], redQ[4];
    __shared__ float s_mu, s_rs;

    const int b = blockIdx.x, t = threadIdx.x;
    const float* xb = x + b*NN;
    const float* ab = agg + b*NN;
    for (int n = t; n < NN; n += 256) { xs[n] = xb[n]; as[n] = ab[n]; }
    if (t < CC1*MM) gw1[t] = gc1_w[t];
    if (t >= 192 && t < 192+CC1) { int o = t-192; gb1[o]=gc1_b[o]; sb1[o]=BN_SCALE*bn1_g[o]; tb1[o]=bn1_b[o]; }
    if (t >= 208 && t < 208+CC2*CC1) gw2[t-208] = gc2_w[t-208];
    if (t >= 240 && t < 240+CC2) { int p=t-240; gb2[p]=gc2_b[p]; sb2[p]=BN_SCALE*bn2_g[p]; tb2[p]=bn2_b[p]; }

    float wr[MM], br[MM], wo[MM];
    #pragma unroll
    for (int m = 0; m < MM; ++m) { wr[m]=w_rel[m]; br[m]=b_rel[m]; wo[m]=w_root[m]; }
    __syncthreads();

    float S = 0.f, Q = 0.f;
    for (int n = t; n < NN; n += 256) {
        float a = as[n], xv = xs[n];
        #pragma unroll
        for (int m = 0; m < MM; ++m) {
            float h = fmaxf(fmaf(a, wr[m], fmaf(xv, wo[m], br[m])), 0.f);
            S += h; Q += h*h;
        }
    }
    #pragma unroll
    for (int off = 32; off; off >>= 1) { S += __shfl_down(S, off); Q += __shfl_down(Q, off); }
    if ((t & 63) == 0) { redS[t>>6] = S; redQ[t>>6] = Q; }
    __syncthreads();
    if (t == 0) {
        float SS = redS[0]+redS[1]+redS[2]+redS[3];
        float QQ = redQ[0]+redQ[1]+redQ[2]+redQ[3];
        const float inv = 1.f / (float)(NN*MM);
        float mu = SS * inv;
        float var = QQ * inv - mu*mu;
        s_mu = mu; s_rs = rsqrtf(var + LN_EPS);
    }
    __syncthreads();
    const float mu = s_mu, rs = s_rs;

    float* zb = z + (size_t)b * KK1;
    for (int n = t; n < NN; n += 256) {
        float a = as[n], xv = xs[n];
        float hn[MM];
        const float4* g4  = reinterpret_cast<const float4*>(ln_g + n*MM);
        const float4* be4 = reinterpret_cast<const float4*>(ln_b + n*MM);
        #pragma unroll
        for (int q = 0; q < 4; ++q) {
            float4 g = g4[q], be = be4[q];
            float gg[4]  = {g.x, g.y, g.z, g.w};
            float bb_[4] = {be.x, be.y, be.z, be.w};
            #pragma unroll
            for (int j = 0; j < 4; ++j) {
                int m = q*4 + j;
                float h = fmaxf(fmaf(a, wr[m], fmaf(xv, wo[m], br[m])), 0.f);
                hn[m] = (h - mu) * rs * gg[j] + bb_[j];
            }
        }
        float y1[CC1];
        #pragma unroll
        for (int o = 0; o < CC1; ++o) {
            float a1 = gb1[o];
            #pragma unroll
            for (int m = 0; m < MM; ++m) a1 = fmaf(gw1[o*MM+m], hn[m], a1);
            y1[o] = fmaxf(a1, 0.f) * sb1[o] + tb1[o];
        }
        #pragma unroll
        for (int p = 0; p < CC2; ++p) {
            float a2 = gb2[p];
            #pragma unroll
            for (int o = 0; o < CC1; ++o) a2 = fmaf(gw2[p*CC1+o], y1[o], a2);
            zb[p*NN + n] = fmaxf(a2, 0.f) * sb2[p] + tb2[p];
        }
    }
}

__global__ __launch_bounds__(256)
void k_fc1(const float* __restrict__ z, const float* __restrict__ W1,
           float* __restrict__ out1_raw)
{
    __shared__ float zs[64*36];
    __shared__ float ws_[32*68];
    const int bt = blockIdx.x, jt = blockIdx.y, ks = blockIdx.z;
    const int t = threadIdx.x;
    const int tb = t >> 4, tj = t & 15;
    const int k0 = ks * GK_CHUNK;
    const int kend = min(k0 + GK_CHUNK, KK1);
    float acc[4][4] = {};
    const int zrow = t >> 2, zcol = (t & 3) * 8;
    const int wrow = t >> 3, wcol = (t & 7) * 8;

    for (int kc = k0; kc < kend; kc += 32) {
        const float* zsrc = z + (size_t)(bt*64 + zrow)*KK1 + kc + zcol;
        #pragma unroll
        for (int q = 0; q < 2; ++q) {
            int k = kc + zcol + q*4;
            float4 v;
            if (k + 3 < kend) v = *reinterpret_cast<const float4*>(zsrc + q*4);
            else {
                v.x = (k+0 < kend) ? zsrc[q*4+0] : 0.f;
                v.y = (k+1 < kend) ? zsrc[q*4+1] : 0.f;
                v.z = (k+2 < kend) ? zsrc[q*4+2] : 0.f;
                v.w = (k+3 < kend) ? zsrc[q*4+3] : 0.f;
            }
            *reinterpret_cast<float4*>(&zs[zrow*36 + zcol + q*4]) = v;
        }
        {
            int k = kc + wrow;
            const float* wsrc = W1 + (size_t)k*HH1 + jt*64 + wcol;
            #pragma unroll
            for (int q = 0; q < 2; ++q) {
                float4 v;
                if (k < kend) v = *reinterpret_cast<const float4*>(wsrc + q*4);
                else v = float4{0.f,0.f,0.f,0.f};
                *reinterpret_cast<float4*>(&ws_[wrow*68 + wcol + q*4]) = v;
            }
        }
        __syncthreads();
        #pragma unroll
        for (int kk = 0; kk < 32; ++kk) {
            float4 w4 = *reinterpret_cast<const float4*>(&ws_[kk*68 + tj*4]);
            float zv[4], wv[4] = {w4.x, w4.y, w4.z, w4.w};
            #pragma unroll
            for (int ib = 0; ib < 4; ++ib) zv[ib] = zs[(tb*4+ib)*36 + kk];
            #pragma unroll
            for (int ib = 0; ib < 4; ++ib)
                #pragma unroll
                for (int ij = 0; ij < 4; ++ij)
                    acc[ib][ij] = fmaf(zv[ib], wv[ij], acc[ib][ij]);
        }
        __syncthreads();
    }
    #pragma unroll
    for (int ib = 0; ib < 4; ++ib) {
        int row = bt*64 + tb*4 + ib;
        #pragma unroll
        for (int ij = 0; ij < 4; ++ij)
            unsafeAtomicAdd(&out1_raw[row*HH1 + jt*64 + tj*4 + ij], acc[ib][ij]);
    }
}

__global__ __launch_bounds__(256)
void k_tail(const float* __restrict__ out1_raw,
            const float* __restrict__ fc_b1, const float* __restrict__ fbn1_g,
            const float* __restrict__ fbn1_b,
            const float* __restrict__ W2, const float* __restrict__ fc_b2,
            const float* __restrict__ fbn2_g, const float* __restrict__ fbn2_b,
            const float* __restrict__ fc1_w, const float* __restrict__ fc1_b,
            float* __restrict__ out)
{
    __shared__ float o1s[HH1];
    const int b = blockIdx.x, t = threadIdx.x;
    float raw = out1_raw[b*HH1 + t] + fc_b1[t];
    o1s[t] = fmaxf(raw * (BN_SCALE * fbn1_g[t]) + fbn1_b[t], 0.f);
    __syncthreads();
    if (t < HH2) {
        float acc = fc_b2[t];
        #pragma unroll 4
        for (int j = 0; j < HH1; ++j) acc = fmaf(o1s[j], W2[j*HH2 + t], acc);
        float v2 = fmaxf(acc * (BN_SCALE * fbn2_g[t]) + fbn2_b[t], 0.f);
        float c = v2 * fc1_w[t];
        #pragma unroll
        for (int off = 32; off; off >>= 1) c += __shfl_down(c, off);
        if (t == 0) out[b] = c + fc1_b[0];
    }
}

extern "C" void kernel_launch(void* const* d_in, const int* in_sizes, int n_in,
                              void* d_out, int out_size, void* d_ws, size_t ws_size,
                              hipStream_t stream)
{
    const float* x      = (const float*)d_in[0];
    const int*   ei     = (const int*)  d_in[1];
    const float* ew     = (const float*)d_in[2];
    const float* w_root = (const float*)d_in[3];
    const float* w_rel  = (const float*)d_in[4];
    const float* b_rel  = (const float*)d_in[5];
    const float* ln_g   = (const float*)d_in[6];
    const float* ln_b   = (const float*)d_in[7];
    const float* gc1_w  = (const float*)d_in[8];
    const float* gc1_b  = (const float*)d_in[9];
    const float* bn1_g  = (const float*)d_in[10];
    const float* bn1_b  = (const float*)d_in[11];
    const float* gc2_w  = (const float*)d_in[12];
    const float* gc2_b  = (const float*)d_in[13];
    const float* bn2_g  = (const float*)d_in[14];
    const float* bn2_b  = (const float*)d_in[15];
    const float* fc_w1  = (const float*)d_in[16];
    const float* fc_b1  = (const float*)d_in[17];
    const float* fbn1_g = (const float*)d_in[18];
    const float* fbn1_b = (const float*)d_in[19];
    const float* fc_w2  = (const float*)d_in[20];
    const float* fc_b2  = (const float*)d_in[21];
    const float* fbn2_g = (const float*)d_in[22];
    const float* fbn2_b = (const float*)d_in[23];
    const float* fc1_w  = (const float*)d_in[24];
    const float* fc1_b  = (const float*)d_in[25];
    float* out = (float*)d_out;

    char* ws = (char*)d_ws;
    const size_t off_pairs = 0;                                   // 256*CAP*8 = 139,460,608
    const size_t off_glen  = off_pairs + (size_t)NBK*CAP*8;       // +4096
    const size_t off_zbuf  = off_glen + 4096;                     // +9,039,872
    const size_t off_op    = off_zbuf + (size_t)BB*KK1*4;         // +31*65536*4
    const size_t need      = off_op + (size_t)31*HH1*256*4;

    if (ws_size >= need) {
        uint2*        pairs = (uint2*)(ws + off_pairs);
        unsigned int* glen  = (unsigned int*)(ws + off_glen);
        float*        zbuf  = (float*)(ws + off_zbuf);
        float*        o1p   = (float*)(ws + off_op);

        hipMemsetAsync(glen, 0, 4096, stream);
        k_bin2<<<EE/EPB, TPB, 0, stream>>>(ei, ei + EE, ew, x, pairs, glen);
        k_sample_fused<<<BB, 512, 0, stream>>>(x, pairs, glen,
                                         w_root, w_rel, b_rel, ln_g, ln_b,
                                         gc1_w, gc1_b, bn1_g, bn1_b,
                                         gc2_w, gc2_b, bn2_g, bn2_b, zbuf);
        k_fc1_part<<<dim3(4,4,31), 256, 0, stream>>>(zbuf, fc_w1, o1p);
        k_tail_part<<<BB, 256, 0, stream>>>(o1p, fc_b1, fbn1_g, fbn1_b,
                                       fc_w2, fc_b2, fbn2_g, fbn2_b,
                                       fc1_w, fc1_b, out);
    } else {
        // round-1 fallback (proven <= 11.6 MB ws)
        float* agg      = (float*)(ws);
        float* zbuf     = (float*)(ws + 2259968);
        float* out1_raw = (float*)(ws + 2259968 + 9039872);

        hipMemsetAsync(agg,      0, (size_t)BB*NN*sizeof(float),  stream);
        hipMemsetAsync(out1_raw, 0, (size_t)BB*HH1*sizeof(float), stream);

        k_edge<<<EE/4/256, 256, 0, stream>>>(ei, ei + EE, ew, x, agg);
        k_sample<<<BB, 256, 0, stream>>>(x, agg, w_root, w_rel, b_rel, ln_g, ln_b,
                                         gc1_w, gc1_b, bn1_g, bn1_b,
                                         gc2_w, gc2_b, bn2_g, bn2_b, zbuf);
        k_fc1<<<dim3(4,4,31), 256, 0, stream>>>(zbuf, fc_w1, out1_raw);
        k_tail<<<BB, 256, 0, stream>>>(out1_raw, fc_b1, fbn1_g, fbn1_b,
                                       fc_w2, fc_b2, fbn2_g, fbn2_b,
                                       fc1_w, fc1_b, out);
    }
}